// Round 5
// baseline (424.229 us; speedup 1.0000x reference)
//
#include <hip/hip_runtime.h>
#include <stdint.h>

typedef unsigned short u16;
typedef float f32x4 __attribute__((ext_vector_type(4)));
typedef __bf16 bf16x8 __attribute__((ext_vector_type(8)));

__device__ __forceinline__ float b2f(u16 u) {
    union { unsigned int i; float f; } w; w.i = ((unsigned int)u) << 16; return w.f;
}
__device__ __forceinline__ u16 f2b(float f) {
    union { float f; unsigned int i; } w; w.f = f;
    unsigned int r = w.i + 0x7fffu + ((w.i >> 16) & 1u);
    return (u16)(r >> 16);
}
__device__ __forceinline__ void gload16(const void* g, void* l) {
    __builtin_amdgcn_global_load_lds(
        (const __attribute__((address_space(1))) unsigned int*)g,
        (__attribute__((address_space(3))) unsigned int*)l, 16, 0, 0);
}

// ---------------- prep: transpose+cast 4 weights, pack biases, zero scratch ----------------
__global__ __launch_bounds__(256) void prep_k(
    const float* __restrict__ Wq, const float* __restrict__ Wk, const float* __restrict__ Wv,
    const float* __restrict__ Wo, const float* __restrict__ bq, const float* __restrict__ bk,
    const float* __restrict__ bv, const float* __restrict__ ob,
    u16* __restrict__ WqkvT, u16* __restrict__ WoT, float* __restrict__ biasAll,
    float* __restrict__ zeroBase)
{
    int bz = blockIdx.x, tid = threadIdx.x;
    if (bz < 4096) {
        int z = bz >> 10, rem = bz & 1023;
        const float* src = (z == 0) ? Wq : (z == 1) ? Wk : (z == 2) ? Wv : Wo;
        u16* dst = (z < 3) ? (WqkvT + (size_t)z * 1024 * 1024) : WoT;
        __shared__ u16 tile[32][33];
        int tx = tid & 31, ty = tid >> 5;  // 32 x 8
        int n0 = (rem & 31) * 32, k0 = (rem >> 5) * 32;
#pragma unroll
        for (int i = 0; i < 4; i++) tile[ty + 8 * i][tx] = f2b(src[(size_t)(k0 + ty + 8 * i) * 1024 + n0 + tx]);
        __syncthreads();
#pragma unroll
        for (int i = 0; i < 4; i++) dst[(size_t)(n0 + ty + 8 * i) * 1024 + k0 + tx] = tile[tx][ty + 8 * i];
    } else if (bz < 4112) {
        int i = (bz - 4096) * 256 + tid;
        float v;
        if (i < 1024) v = bq[i];
        else if (i < 2048) v = bk[i - 1024];
        else if (i < 3072) v = bv[i - 2048];
        else v = ob[i - 3072];
        biasAll[i] = v;
    } else {
        int e = (bz - 4112) * 256 + tid;           // float4 index
        ((float4*)zeroBase)[e] = make_float4(0.f, 0.f, 0.f, 0.f);
    }
}

// ---------------- LayerNorm(x fp32) -> xn (bf16), one row per block ----------------
__global__ __launch_bounds__(256) void ln_x(
    const float* __restrict__ x, const float* __restrict__ g, const float* __restrict__ bt,
    u16* __restrict__ xn)
{
    int row = blockIdx.x, tid = threadIdx.x;
    const float* xr = x + (size_t)row * 1024;
    float4 u = *(const float4*)(xr + tid * 4);
    float v0 = u.x, v1 = u.y, v2 = u.z, v3 = u.w;
    float s = v0 + v1 + v2 + v3;
    float s2 = v0 * v0 + v1 * v1 + v2 * v2 + v3 * v3;
#pragma unroll
    for (int m = 32; m > 0; m >>= 1) { s += __shfl_xor(s, m, 64); s2 += __shfl_xor(s2, m, 64); }
    __shared__ float red[8];
    int w = tid >> 6, lane = tid & 63;
    if (lane == 0) { red[w] = s; red[4 + w] = s2; }
    __syncthreads();
    s = red[0] + red[1] + red[2] + red[3];
    s2 = red[4] + red[5] + red[6] + red[7];
    float mean = s * (1.f / 1024.f);
    float var = s2 * (1.f / 1024.f) - mean * mean;
    float rstd = rsqrtf(var + 1e-5f);
    int c = tid * 4;
    float4 gg = *(const float4*)(g + c);
    float4 bb = *(const float4*)(bt + c);
    ushort4 o;
    o.x = f2b((v0 - mean) * rstd * gg.x + bb.x);
    o.y = f2b((v1 - mean) * rstd * gg.y + bb.y);
    o.z = f2b((v2 - mean) * rstd * gg.z + bb.z);
    o.w = f2b((v3 - mean) * rstd * gg.w + bb.w);
    *(ushort4*)(xn + (size_t)row * 1024 + c) = o;
}

// ---------------- 256x256 MFMA GEMM, BK=64, 8 waves, 8-phase counted-vmcnt pipeline ----------
// Main loop identical to the verified 141us version (R1). Epilogues route C through LDS with a
// quad-XOR column-slot swizzle: the VALUE for column-slot j is stored at LDS slot (j^quad),
// so the 4 quads of a wave hit 4 disjoint 8-bank groups (conflict-free). Copy-out reads slot
// (pos ^ quad(row)) to invert. R4's bug: stored value j^quad at slot j^quad (identity) while
// still inverting on read -> scrambled columns. Fixed: value j at slot j^quad.
__global__ __launch_bounds__(512, 2) void gemm256(
    const u16* __restrict__ A, const u16* __restrict__ Bt, const float* __restrict__ bias,
    int mode, u16* __restrict__ Qb, u16* __restrict__ Kb, u16* __restrict__ Vb,
    float* __restrict__ colsum, float* __restrict__ Cf,
    const float* __restrict__ Xf, const float* __restrict__ gate)
{
    const int K = 1024;
    __shared__ __align__(16) u16 L[2][2][256 * 64];   // [buf][0=A,1=B] 128 KB total
    int tid = threadIdx.x, lane = tid & 63, w = tid >> 6;
    int wm = w >> 2, wn = w & 3;
    // XCD swizzle: each XCD owns 8 row-tiles (4MB of A), walks cols outer.
    int NB = gridDim.x;
    int lid = blockIdx.y * NB + blockIdx.x;
    int xcd = lid & 7;
    int i_ = lid >> 3;
    int rowLocal = i_ & 7;
    int colIdx = i_ >> 3;
    size_t rowbase = (size_t)(xcd * 8 + rowLocal) * 256;
    size_t colbase = (size_t)colIdx * 256;
    const u16* Ab = A + rowbase * K;
    const u16* Bb = Bt + colbase * K;
    f32x4 acc[8][4] = {};
    int quad = lane >> 4, mr = lane & 15, swK = mr & 7;
    int srow = lane >> 3;
    int scol = ((lane & 7) ^ srow) * 8;   // pre-swizzled global col (16B blocks)
    u16* A0 = L[0][0]; u16* B0 = L[0][1]; u16* A1 = L[1][0]; u16* B1 = L[1][1];

#define STAGE(ldsmat, gbase, hf, k0) do { \
    _Pragma("unroll") \
    for (int r_ = 0; r_ < 2; r_++) { \
        int rb_ = (hf) * 128 + r_ * 64 + w * 8; \
        gload16((gbase) + (size_t)(rb_ + srow) * 1024 + (k0) + scol, (ldsmat) + rb_ * 64); \
    } } while (0)

#define LDA(dst, src, mh) do { \
    _Pragma("unroll") \
    for (int i2_ = 0; i2_ < 4; i2_++) \
    _Pragma("unroll") \
    for (int kq_ = 0; kq_ < 2; kq_++) \
        dst[i2_ * 2 + kq_] = *(const bf16x8*)&(src)[(wm * 128 + (mh) * 64 + i2_ * 16 + mr) * 64 + (((kq_ * 4 + quad) ^ swK) * 8)]; \
    } while (0)

#define LDB(dst, src, nh) do { \
    _Pragma("unroll") \
    for (int j_ = 0; j_ < 2; j_++) \
    _Pragma("unroll") \
    for (int kq_ = 0; kq_ < 2; kq_++) \
        dst[j_ * 2 + kq_] = *(const bf16x8*)&(src)[(wn * 64 + (nh) * 32 + j_ * 16 + mr) * 64 + (((kq_ * 4 + quad) ^ swK) * 8)]; \
    } while (0)

#define MM(mh, nh, av, bv) do { \
    __builtin_amdgcn_s_setprio(1); \
    _Pragma("unroll") \
    for (int i2_ = 0; i2_ < 4; i2_++) \
    _Pragma("unroll") \
    for (int j_ = 0; j_ < 2; j_++) \
    _Pragma("unroll") \
    for (int kq_ = 0; kq_ < 2; kq_++) \
        acc[(mh) * 4 + i2_][(nh) * 2 + j_] = __builtin_amdgcn_mfma_f32_16x16x32_bf16( \
            av[i2_ * 2 + kq_], bv[j_ * 2 + kq_], acc[(mh) * 4 + i2_][(nh) * 2 + j_], 0, 0, 0); \
    __builtin_amdgcn_s_setprio(0); } while (0)

#define BAR() asm volatile("s_barrier" ::: "memory")
#define VMW(n) asm volatile("s_waitcnt vmcnt(" #n ")" ::: "memory")

    // prologue: tile0 (A+B) -> buf0, tile1 B -> buf1
    STAGE(A0, Ab, 0, 0); STAGE(A0, Ab, 1, 0);
    STAGE(B0, Bb, 0, 0); STAGE(B0, Bb, 1, 0);
    STAGE(B1, Bb, 0, 64); STAGE(B1, Bb, 1, 64);
    VMW(4);   // oldest 8 loads (all of tile0) landed
    BAR();

    bf16x8 a[8], bn0[4], bn1[4];
    for (int t = 0; t < 8; ++t) {
        int k0 = t * 128;
        bool last = (t == 7);
        // ---- tile 2t from buf0 ----
        LDA(a, A0, 0); LDB(bn0, B0, 0);
        STAGE(A1, Ab, 0, k0 + 64);
        BAR(); MM(0, 0, a, bn0); BAR();
        LDB(bn1, B0, 1);
        STAGE(A1, Ab, 1, k0 + 64);
        BAR(); MM(0, 1, a, bn1); BAR();
        LDA(a, A0, 1);
        if (!last) STAGE(B0, Bb, 0, k0 + 128);
        BAR(); MM(1, 1, a, bn1); BAR();
        if (!last) STAGE(B0, Bb, 1, k0 + 128);
        BAR(); MM(1, 0, a, bn0);
        if (last) { VMW(0); } else { VMW(4); }
        BAR();
        // ---- tile 2t+1 from buf1 ----
        LDA(a, A1, 0); LDB(bn0, B1, 0);
        if (!last) STAGE(A0, Ab, 0, k0 + 128);
        BAR(); MM(0, 0, a, bn0); BAR();
        LDB(bn1, B1, 1);
        if (!last) STAGE(A0, Ab, 1, k0 + 128);
        BAR(); MM(0, 1, a, bn1); BAR();
        LDA(a, A1, 1);
        if (!last) STAGE(B1, Bb, 0, k0 + 192);
        BAR(); MM(1, 1, a, bn1); BAR();
        if (!last) STAGE(B1, Bb, 1, k0 + 192);
        BAR(); MM(1, 0, a, bn0);
        if (!last) VMW(4);
        BAR();
    }
#undef STAGE
#undef LDA
#undef LDB
#undef MM
#undef BAR
#undef VMW

    int colj[4]; float bj[4];
#pragma unroll
    for (int j = 0; j < 4; j++) { colj[j] = (int)colbase + wn * 64 + j * 16 + mr; bj[j] = bias[colj[j]]; }
    int creg = (int)colbase + wn * 64;   // wave-uniform region start
    if (mode == 0) {
        // Stage C tile (256x256 bf16 = 128KB) in LDS (quad-XOR slot swizzle), coalesced copy-out.
        u16* Ct = (u16*)L;
        if (creg < 1024) {
            // Q + feature softmax over this wave's 64-col head span
#pragma unroll
            for (int i = 0; i < 8; i++) {
#pragma unroll
                for (int r = 0; r < 4; r++) {
                    int lr = wm * 128 + i * 16 + quad * 4 + r;
                    float v[4], m = -1e30f, ss = 0.f;
#pragma unroll
                    for (int j = 0; j < 4; j++) { v[j] = acc[i][j][r] + bj[j]; m = fmaxf(m, v[j]); }
#pragma unroll
                    for (int s = 1; s < 16; s <<= 1) m = fmaxf(m, __shfl_xor(m, s, 64));
#pragma unroll
                    for (int j = 0; j < 4; j++) { v[j] = __expf(v[j] - m); ss += v[j]; }
#pragma unroll
                    for (int s = 1; s < 16; s <<= 1) ss += __shfl_xor(ss, s, 64);
                    float inv = 1.f / ss;
#pragma unroll
                    for (int j = 0; j < 4; j++)
                        Ct[lr * 256 + wn * 64 + ((j ^ quad) * 16) + mr] = f2b(v[j] * inv);
                }
            }
        } else if (creg < 2048) {
            // K: store exp(k) bf16; accumulate per-column exp-sums -> colsum
            int b_ = (int)(rowbase >> 12);
            float csum[4] = {};
#pragma unroll
            for (int i = 0; i < 8; i++) {
#pragma unroll
                for (int r = 0; r < 4; r++) {
                    int lr = wm * 128 + i * 16 + quad * 4 + r;
#pragma unroll
                    for (int j = 0; j < 4; j++) {
                        float e = __expf(acc[i][j][r] + bj[j]);
                        Ct[lr * 256 + wn * 64 + ((j ^ quad) * 16) + mr] = f2b(e);
                        csum[j] += e;
                    }
                }
            }
#pragma unroll
            for (int j = 0; j < 4; j++) {
                csum[j] += __shfl_xor(csum[j], 16, 64);
                csum[j] += __shfl_xor(csum[j], 32, 64);
                if (quad == 0) atomicAdd(&colsum[b_ * 1024 + (colj[j] - 1024)], csum[j]);
            }
        } else {
            // V: plain store
#pragma unroll
            for (int i = 0; i < 8; i++) {
#pragma unroll
                for (int r = 0; r < 4; r++) {
                    int lr = wm * 128 + i * 16 + quad * 4 + r;
#pragma unroll
                    for (int j = 0; j < 4; j++)
                        Ct[lr * 256 + wn * 64 + ((j ^ quad) * 16) + mr] = f2b(acc[i][j][r] + bj[j]);
                }
            }
        }
        __syncthreads();
        u16* dst = (colIdx < 4) ? Qb : (colIdx < 8) ? Kb : Vb;
        int dcol0 = (int)colbase & 1023;
#pragma unroll
        for (int k = 0; k < 16; ++k) {
            int e = k * 512 + tid;        // 16B chunks: 256 rows x 32 chunks
            int row = e >> 5, pos = e & 31;
            int posl = pos ^ (((row >> 2) & 3) << 1);   // invert quad slot swizzle
            *(uint4*)&dst[(rowbase + row) * 1024 + dcol0 + pos * 8] =
                *(const uint4*)&Ct[row * 256 + posl * 8];
        }
        return;
    }
    // mode 2: out = Xf + gate * (A@B + bias); two 128-row LDS passes (128x256 f32 = 128KB),
    // Xf read + Cf write fused into the coalesced copy-out. (quad&1)-XOR slot swizzle.
    {
        float* Cs32 = (float*)L;
        int b_ = (int)(rowbase >> 12);
        int q1 = quad & 1;
#pragma unroll 1
        for (int pass = 0; pass < 2; ++pass) {
            if (wm == pass) {
#pragma unroll
                for (int i = 0; i < 8; i++) {
#pragma unroll
                    for (int r = 0; r < 4; r++) {
                        int lr = i * 16 + quad * 4 + r;   // 0..127 within half
#pragma unroll
                        for (int j = 0; j < 4; j++)
                            Cs32[lr * 256 + wn * 64 + ((j ^ q1) * 16) + mr] = acc[i][j][r] + bj[j];
                    }
                }
            }
            __syncthreads();
#pragma unroll
            for (int k = 0; k < 16; ++k) {
                int e = k * 512 + tid;     // 16B chunks: 128 rows x 64 chunks
                int row = e >> 6, pos = e & 63;
                int posl = pos ^ (((row >> 2) & 1) << 2);   // invert slot swizzle
                size_t grow = rowbase + pass * 128 + row;
                int col = (int)colbase + pos * 4;
                float4 c4 = *(const float4*)&Cs32[row * 256 + posl * 4];
                float4 xf = *(const float4*)&Xf[grow * 1024 + col];
                float4 g4 = *(const float4*)&gate[b_ * 1024 + col];
                float4 o;
                o.x = xf.x + g4.x * c4.x;
                o.y = xf.y + g4.y * c4.y;
                o.z = xf.z + g4.z * c4.z;
                o.w = xf.w + g4.w * c4.w;
                *(float4*)&Cf[grow * 1024 + col] = o;
            }
            __syncthreads();
        }
    }
}

// ---------------- ctx[b,h] = (expK * inv_colsum)^T V ----------------
__global__ __launch_bounds__(256) void ctx_k(
    const u16* __restrict__ kbuf, const u16* __restrict__ vbuf,
    const float* __restrict__ colsum, float* __restrict__ ctx)
{
    int ch = blockIdx.x, h = blockIdx.y, b = blockIdx.z;
    __shared__ __align__(16) float Es[16][64];
    __shared__ __align__(16) float Vs[16][64];
    int tid = threadIdx.x;
    int td = tid >> 4, tl = tid & 15;
    int lr = tid >> 4, lc = (tid & 15) * 4;    // vectorized load: row 0..15, 4-col group
    const float* cs = colsum + b * 1024 + h * 64 + lc;
    float4 inv4 = make_float4(1.f / cs[0], 1.f / cs[1], 1.f / cs[2], 1.f / cs[3]);
    float acc[4][4] = {};
    size_t rowbase = (size_t)b * 4096 + ch * 512;
    for (int g = 0; g < 32; ++g) {
        size_t base = (rowbase + g * 16 + lr) * 1024 + h * 64 + lc;
        ushort4 kv = *(const ushort4*)&kbuf[base];
        ushort4 vv = *(const ushort4*)&vbuf[base];
        *(float4*)&Es[lr][lc] = make_float4(b2f(kv.x) * inv4.x, b2f(kv.y) * inv4.y,
                                            b2f(kv.z) * inv4.z, b2f(kv.w) * inv4.w);
        *(float4*)&Vs[lr][lc] = make_float4(b2f(vv.x), b2f(vv.y), b2f(vv.z), b2f(vv.w));
        __syncthreads();
#pragma unroll
        for (int n = 0; n < 16; n++) {
            f32x4 e4 = *(const f32x4*)&Es[n][td * 4];
            f32x4 v4 = *(const f32x4*)&Vs[n][tl * 4];
#pragma unroll
            for (int i = 0; i < 4; i++)
#pragma unroll
                for (int j = 0; j < 4; j++) acc[i][j] += e4[i] * v4[j];
        }
        __syncthreads();
    }
    float* cb = ctx + (size_t)(b * 16 + h) * 4096;
#pragma unroll
    for (int i = 0; i < 4; i++)
#pragma unroll
        for (int j = 0; j < 4; j++)
            atomicAdd(&cb[(td * 4 + i) * 64 + tl * 4 + j], acc[i][j]);
}

// ---------------- emb_out = silu(emb) @ emb_W (fp32, atomic over k chunks) ----------------
__global__ __launch_bounds__(256) void embout_k(
    const float* __restrict__ emb, const float* __restrict__ embW, float* __restrict__ eo)
{
    int cb = blockIdx.x, kc = blockIdx.y;   // 8 col-blocks x 32 k-chunks of 32
    __shared__ float semb[128];
    int tid = threadIdx.x;
    if (tid < 128) {
        int b = tid >> 5, kk = tid & 31;
        float xv = emb[b * 1024 + kc * 32 + kk];
        semb[tid] = xv / (1.f + __expf(-xv));
    }
    __syncthreads();
    int o = cb * 256 + tid;
    float a0 = 0, a1 = 0, a2 = 0, a3 = 0;
    for (int kk = 0; kk < 32; kk++) {
        float wv = embW[(size_t)(kc * 32 + kk) * 2048 + o];
        a0 += semb[kk] * wv; a1 += semb[32 + kk] * wv;
        a2 += semb[64 + kk] * wv; a3 += semb[96 + kk] * wv;
    }
    atomicAdd(&eo[o], a0);
    atomicAdd(&eo[2048 + o], a1);
    atomicAdd(&eo[4096 + o], a2);
    atomicAdd(&eo[6144 + o], a3);
}

// ---------------- y = q_soft @ ctx per head (MFMA, K=64), XOR bank-swizzled Qs ----------------
__global__ __launch_bounds__(256) void y_k(
    const u16* __restrict__ q, const float* __restrict__ ctx, u16* __restrict__ y)
{
    int mc = blockIdx.x, h = blockIdx.y, b = blockIdx.z;
    __shared__ __align__(16) u16 Qs[128 * 64];
    __shared__ __align__(16) u16 Cs[64 * 72];
    int tid = threadIdx.x, lane = tid & 63, w = tid >> 6;
    size_t row0 = (size_t)b * 4096 + (size_t)mc * 128;
    const u16* Qb = q + row0 * 1024 + h * 64;
    int sr = tid >> 3, g_ = tid & 7;
    int scb = (g_ ^ (sr & 7)) * 8;   // LDS col block (swizzled); global col = g_*8
#pragma unroll
    for (int p = 0; p < 4; p++) {
        int r = p * 32 + sr;
        *(uint4*)&Qs[r * 64 + scb] = *(const uint4*)&Qb[(size_t)r * 1024 + g_ * 8];
    }
    const float* Cb = ctx + (size_t)(b * 16 + h) * 4096;
#pragma unroll
    for (int rep = 0; rep < 16; ++rep) {
        int e = tid + rep * 256;
        int d = e >> 6, l = e & 63;
        Cs[l * 72 + d] = f2b(Cb[e]);   // transposed: Cs[n=l][k=d]
    }
    __syncthreads();
    int quad = lane >> 4, mr = lane & 15;
    int swA = mr & 7;
    f32x4 acc[2][4] = {};
#pragma unroll
    for (int kk = 0; kk < 64; kk += 32) {
        bf16x8 a[2], bb[4];
#pragma unroll
        for (int i = 0; i < 2; i++)
            a[i] = *(const bf16x8*)&Qs[(w * 32 + i * 16 + mr) * 64 + ((((kk >> 3) + quad) ^ swA) * 8)];
#pragma unroll
        for (int j = 0; j < 4; j++) bb[j] = *(const bf16x8*)&Cs[(j * 16 + mr) * 72 + kk + quad * 8];
#pragma unroll
        for (int i = 0; i < 2; i++)
#pragma unroll
            for (int j = 0; j < 4; j++)
                acc[i][j] = __builtin_amdgcn_mfma_f32_16x16x32_bf16(a[i], bb[j], acc[i][j], 0, 0, 0);
    }
#pragma unroll
    for (int i = 0; i < 2; i++)
#pragma unroll
        for (int j = 0; j < 4; j++)
#pragma unroll
            for (int r = 0; r < 4; r++) {
                size_t row = row0 + w * 32 + i * 16 + quad * 4 + r;
                int col = h * 64 + j * 16 + mr;
                y[row * 1024 + col] = f2b(acc[i][j][r]);
            }
}

// ---------------- h_in = silu( LN(y)*sn_g+sn_b )*(1+scale)+shift ), bf16 in place ----------------
__global__ __launch_bounds__(256) void style_k(
    u16* __restrict__ y, const float* __restrict__ eo, const float* __restrict__ embb,
    const float* __restrict__ sng, const float* __restrict__ snb)
{
    int row = blockIdx.x, tid = threadIdx.x, b = row >> 12;
    u16* yr = y + (size_t)row * 1024;
    ushort4 u = *(const ushort4*)(yr + tid * 4);
    float vv[4] = { b2f(u.x), b2f(u.y), b2f(u.z), b2f(u.w) };
    float s = vv[0] + vv[1] + vv[2] + vv[3];
    float s2 = vv[0] * vv[0] + vv[1] * vv[1] + vv[2] * vv[2] + vv[3] * vv[3];
#pragma unroll
    for (int m = 32; m > 0; m >>= 1) { s += __shfl_xor(s, m, 64); s2 += __shfl_xor(s2, m, 64); }
    __shared__ float red[8];
    int w = tid >> 6, lane = tid & 63;
    if (lane == 0) { red[w] = s; red[4 + w] = s2; }
    __syncthreads();
    s = red[0] + red[1] + red[2] + red[3];
    s2 = red[4] + red[5] + red[6] + red[7];
    float mean = s * (1.f / 1024.f);
    float var = s2 * (1.f / 1024.f) - mean * mean;
    float rstd = rsqrtf(var + 1e-5f);
    int c = tid * 4;
    ushort4 o;
    u16* op = (u16*)&o;
#pragma unroll
    for (int i = 0; i < 4; i++) {
        int cc = c + i;
        float scale = eo[b * 2048 + cc] + embb[cc];
        float shift = eo[b * 2048 + 1024 + cc] + embb[1024 + cc];
        float hn = (vv[i] - mean) * rstd * sng[cc] + snb[cc];
        float hh = hn * (1.f + scale) + shift;
        op[i] = f2b(hh / (1.f + __expf(-hh)));
    }
    *(ushort4*)(yr + c) = o;
}

extern "C" void kernel_launch(void* const* d_in, const int* in_sizes, int n_in,
                              void* d_out, int out_size, void* d_ws, size_t ws_size,
                              hipStream_t stream)
{
    const float* x    = (const float*)d_in[0];
    const float* emb  = (const float*)d_in[1];
    const float* gate = (const float*)d_in[2];
    const float* ng   = (const float*)d_in[3];
    const float* nb   = (const float*)d_in[4];
    const float* Wq   = (const float*)d_in[5];
    const float* bq   = (const float*)d_in[6];
    const float* Wk   = (const float*)d_in[7];
    const float* bk   = (const float*)d_in[8];
    const float* Wv   = (const float*)d_in[9];
    const float* bv   = (const float*)d_in[10];
    const float* embW = (const float*)d_in[11];
    const float* embB = (const float*)d_in[12];
    const float* sng  = (const float*)d_in[13];
    const float* snb  = (const float*)d_in[14];
    const float* Wo   = (const float*)d_in[15];
    const float* ob   = (const float*)d_in[16];
    float* out = (float*)d_out;

    uint8_t* ws = (uint8_t*)d_ws;
    size_t off = 0;
    auto alloc = [&](size_t bytes) { void* p = ws + off; off += (bytes + 255) & ~(size_t)255; return p; };
    u16*   WqkvT   = (u16*)alloc(3072ull * 1024 * 2);    // 6 MB (qT | kT | vT) bf16
    u16*   WoT     = (u16*)alloc(1024ull * 1024 * 2);    // 2 MB bf16
    float* biasAll = (float*)alloc(4096 * 4);            // 16 KB
    // contiguous zero region: colsum | ctx | embout
    float* colsum  = (float*)alloc(4096 * 4);            // 16 KB
    float* ctx     = (float*)alloc(64ull * 64 * 64 * 4); // 1 MB
    float* embout  = (float*)alloc(4ull * 2048 * 4);     // 32 KB
    u16*   XN      = (u16*)alloc(16384ull * 1024 * 2);   // 32 MB: xn -> y -> h_in
    u16*   BUF0    = (u16*)alloc(16384ull * 1024 * 2);   // 32 MB: Qsoft
    u16*   BUF1    = (u16*)alloc(16384ull * 1024 * 2);   // 32 MB: expK
    u16*   BUF2    = (u16*)alloc(16384ull * 1024 * 2);   // 32 MB: V

    prep_k<<<4380, 256, 0, stream>>>(Wq, Wk, Wv, Wo, bq, bk, bv, ob, WqkvT, WoT, biasAll, colsum);
    ln_x<<<16384, 256, 0, stream>>>(x, ng, nb, XN);
    gemm256<<<dim3(12, 64), 512, 0, stream>>>(XN, WqkvT, biasAll, 0,
                                              BUF0, BUF1, BUF2, colsum, nullptr, nullptr, nullptr);
    ctx_k<<<dim3(8, 16, 4), 256, 0, stream>>>(BUF1, BUF2, colsum, ctx);
    embout_k<<<dim3(8, 32), 256, 0, stream>>>(emb, embW, embout);
    y_k<<<dim3(32, 16, 4), 256, 0, stream>>>(BUF0, ctx, XN);
    style_k<<<16384, 256, 0, stream>>>(XN, embout, embB, sng, snb);
    gemm256<<<dim3(4, 64), 512, 0, stream>>>(XN, WoT, biasAll + 3072, 2,
                                             nullptr, nullptr, nullptr, nullptr, out, x, gate);
}

// Round 6
// 416.720 us; speedup vs baseline: 1.0180x; 1.0180x over previous
//
#include <hip/hip_runtime.h>
#include <stdint.h>

typedef unsigned short u16;
typedef float f32x4 __attribute__((ext_vector_type(4)));
typedef __bf16 bf16x8 __attribute__((ext_vector_type(8)));

__device__ __forceinline__ float b2f(u16 u) {
    union { unsigned int i; float f; } w; w.i = ((unsigned int)u) << 16; return w.f;
}
__device__ __forceinline__ u16 f2b(float f) {
    union { float f; unsigned int i; } w; w.f = f;
    unsigned int r = w.i + 0x7fffu + ((w.i >> 16) & 1u);
    return (u16)(r >> 16);
}
__device__ __forceinline__ void gload16(const void* g, void* l) {
    __builtin_amdgcn_global_load_lds(
        (const __attribute__((address_space(1))) unsigned int*)g,
        (__attribute__((address_space(3))) unsigned int*)l, 16, 0, 0);
}

// ---------------- prep: transpose+cast 4 weights, pack biases, zero scratch ----------------
__global__ __launch_bounds__(256) void prep_k(
    const float* __restrict__ Wq, const float* __restrict__ Wk, const float* __restrict__ Wv,
    const float* __restrict__ Wo, const float* __restrict__ bq, const float* __restrict__ bk,
    const float* __restrict__ bv, const float* __restrict__ ob,
    u16* __restrict__ WqkvT, u16* __restrict__ WoT, float* __restrict__ biasAll,
    float* __restrict__ zeroBase)
{
    int bz = blockIdx.x, tid = threadIdx.x;
    if (bz < 4096) {
        int z = bz >> 10, rem = bz & 1023;
        const float* src = (z == 0) ? Wq : (z == 1) ? Wk : (z == 2) ? Wv : Wo;
        u16* dst = (z < 3) ? (WqkvT + (size_t)z * 1024 * 1024) : WoT;
        __shared__ u16 tile[32][33];
        int tx = tid & 31, ty = tid >> 5;  // 32 x 8
        int n0 = (rem & 31) * 32, k0 = (rem >> 5) * 32;
#pragma unroll
        for (int i = 0; i < 4; i++) tile[ty + 8 * i][tx] = f2b(src[(size_t)(k0 + ty + 8 * i) * 1024 + n0 + tx]);
        __syncthreads();
#pragma unroll
        for (int i = 0; i < 4; i++) dst[(size_t)(n0 + ty + 8 * i) * 1024 + k0 + tx] = tile[tx][ty + 8 * i];
    } else if (bz < 4112) {
        int i = (bz - 4096) * 256 + tid;
        float v;
        if (i < 1024) v = bq[i];
        else if (i < 2048) v = bk[i - 1024];
        else if (i < 3072) v = bv[i - 2048];
        else v = ob[i - 3072];
        biasAll[i] = v;
    } else {
        int e = (bz - 4112) * 256 + tid;           // float4 index
        ((float4*)zeroBase)[e] = make_float4(0.f, 0.f, 0.f, 0.f);
    }
}

// ---------------- LayerNorm(x fp32) -> xn (bf16), one row per block ----------------
__global__ __launch_bounds__(256) void ln_x(
    const float* __restrict__ x, const float* __restrict__ g, const float* __restrict__ bt,
    u16* __restrict__ xn)
{
    int row = blockIdx.x, tid = threadIdx.x;
    const float* xr = x + (size_t)row * 1024;
    float4 u = *(const float4*)(xr + tid * 4);
    float v0 = u.x, v1 = u.y, v2 = u.z, v3 = u.w;
    float s = v0 + v1 + v2 + v3;
    float s2 = v0 * v0 + v1 * v1 + v2 * v2 + v3 * v3;
#pragma unroll
    for (int m = 32; m > 0; m >>= 1) { s += __shfl_xor(s, m, 64); s2 += __shfl_xor(s2, m, 64); }
    __shared__ float red[8];
    int w = tid >> 6, lane = tid & 63;
    if (lane == 0) { red[w] = s; red[4 + w] = s2; }
    __syncthreads();
    s = red[0] + red[1] + red[2] + red[3];
    s2 = red[4] + red[5] + red[6] + red[7];
    float mean = s * (1.f / 1024.f);
    float var = s2 * (1.f / 1024.f) - mean * mean;
    float rstd = rsqrtf(var + 1e-5f);
    int c = tid * 4;
    float4 gg = *(const float4*)(g + c);
    float4 bb = *(const float4*)(bt + c);
    ushort4 o;
    o.x = f2b((v0 - mean) * rstd * gg.x + bb.x);
    o.y = f2b((v1 - mean) * rstd * gg.y + bb.y);
    o.z = f2b((v2 - mean) * rstd * gg.z + bb.z);
    o.w = f2b((v3 - mean) * rstd * gg.w + bb.w);
    *(ushort4*)(xn + (size_t)row * 1024 + c) = o;
}

// ---------------- 256x256 MFMA GEMM, BK=64, 8 waves ----------------------------------------
// R6 loop: MM order (0,0)(0,1)(1,0)(1,1); stages front-loaded (A' R1, B' R2); bn1 read one
// region ahead; next-tile aM0/bn0 read at R4 end; single VMW(0) per tile after MM(1,1);
// 4 barriers/tile (classic parity dbuf -> no intra-tile LDS WAR). Only R3's A-reads are
// same-region (register budget: one shared a[8]). Epilogues = verified R5 (quad-XOR slot
// swizzle, conflict-free, coalesced copy-out).
__global__ __launch_bounds__(512, 2) void gemm256(
    const u16* __restrict__ A, const u16* __restrict__ Bt, const float* __restrict__ bias,
    int mode, u16* __restrict__ Qb, u16* __restrict__ Kb, u16* __restrict__ Vb,
    float* __restrict__ colsum, float* __restrict__ Cf,
    const float* __restrict__ Xf, const float* __restrict__ gate)
{
    const int K = 1024;
    __shared__ __align__(16) u16 L[2][2][256 * 64];   // [buf][0=A,1=B] 128 KB total
    int tid = threadIdx.x, lane = tid & 63, w = tid >> 6;
    int wm = w >> 2, wn = w & 3;
    // XCD swizzle: each XCD owns 8 row-tiles (4MB of A), walks cols outer.
    int NB = gridDim.x;
    int lid = blockIdx.y * NB + blockIdx.x;
    int xcd = lid & 7;
    int i_ = lid >> 3;
    int rowLocal = i_ & 7;
    int colIdx = i_ >> 3;
    size_t rowbase = (size_t)(xcd * 8 + rowLocal) * 256;
    size_t colbase = (size_t)colIdx * 256;
    const u16* Ab = A + rowbase * K;
    const u16* Bb = Bt + colbase * K;
    f32x4 acc[8][4] = {};
    int quad = lane >> 4, mr = lane & 15, swK = mr & 7;
    int srow = lane >> 3;
    int scol = ((lane & 7) ^ srow) * 8;   // pre-swizzled global col (16B blocks)
    u16* A0 = L[0][0]; u16* B0 = L[0][1]; u16* A1 = L[1][0]; u16* B1 = L[1][1];

#define STAGE(ldsmat, gbase, hf, k0) do { \
    _Pragma("unroll") \
    for (int r_ = 0; r_ < 2; r_++) { \
        int rb_ = (hf) * 128 + r_ * 64 + w * 8; \
        gload16((gbase) + (size_t)(rb_ + srow) * 1024 + (k0) + scol, (ldsmat) + rb_ * 64); \
    } } while (0)

#define LDA(dst, src, mh) do { \
    _Pragma("unroll") \
    for (int i2_ = 0; i2_ < 4; i2_++) \
    _Pragma("unroll") \
    for (int kq_ = 0; kq_ < 2; kq_++) \
        dst[i2_ * 2 + kq_] = *(const bf16x8*)&(src)[(wm * 128 + (mh) * 64 + i2_ * 16 + mr) * 64 + (((kq_ * 4 + quad) ^ swK) * 8)]; \
    } while (0)

#define LDB(dst, src, nh) do { \
    _Pragma("unroll") \
    for (int j_ = 0; j_ < 2; j_++) \
    _Pragma("unroll") \
    for (int kq_ = 0; kq_ < 2; kq_++) \
        dst[j_ * 2 + kq_] = *(const bf16x8*)&(src)[(wn * 64 + (nh) * 32 + j_ * 16 + mr) * 64 + (((kq_ * 4 + quad) ^ swK) * 8)]; \
    } while (0)

#define MM(mh, nh, av, bv) do { \
    __builtin_amdgcn_s_setprio(1); \
    _Pragma("unroll") \
    for (int i2_ = 0; i2_ < 4; i2_++) \
    _Pragma("unroll") \
    for (int j_ = 0; j_ < 2; j_++) \
    _Pragma("unroll") \
    for (int kq_ = 0; kq_ < 2; kq_++) \
        acc[(mh) * 4 + i2_][(nh) * 2 + j_] = __builtin_amdgcn_mfma_f32_16x16x32_bf16( \
            av[i2_ * 2 + kq_], bv[j_ * 2 + kq_], acc[(mh) * 4 + i2_][(nh) * 2 + j_], 0, 0, 0); \
    __builtin_amdgcn_s_setprio(0); } while (0)

#define BAR() asm volatile("s_barrier" ::: "memory")
#define VMW(n) asm volatile("s_waitcnt vmcnt(" #n ")" ::: "memory")

    // prologue: tile0 (A+B) -> buf0; preload first fragments
    STAGE(A0, Ab, 0, 0); STAGE(A0, Ab, 1, 0);
    STAGE(B0, Bb, 0, 0); STAGE(B0, Bb, 1, 0);
    VMW(0);
    BAR();

    bf16x8 a[8], bn0[4], bn1[4];
    LDA(a, A0, 0); LDB(bn0, B0, 0);

    // Per tile T (cur = bufs of T, nxt = bufs of T+1):
    //  R1: stage A'(h0,h1) | LDB(bn1,cur) | MM(0,0)[a=aM0,bn0]      | BAR
    //  R2: stage B'(h0,h1) |               MM(0,1)[a,bn1]            | BAR   (a dead)
    //  R3: LDA(a<-cur,mh1) |               MM(1,0)[a,bn0]            | BAR   (bn0 dead)
    //  R4: MM(1,1)[a,bn1]  | VMW(0) | LDA(a<-nxt,0); LDB(bn0<-nxt,0)| BAR
#define TILE(T, cA, cB, nA, nB) do { \
    const int kN_ = ((T) + 1) * 64; \
    /* R1 */ \
    if ((T) < 15) { STAGE(nA, Ab, 0, kN_); STAGE(nA, Ab, 1, kN_); } \
    LDB(bn1, cB, 1); \
    MM(0, 0, a, bn0); \
    BAR(); \
    /* R2 */ \
    if ((T) < 15) { STAGE(nB, Bb, 0, kN_); STAGE(nB, Bb, 1, kN_); } \
    MM(0, 1, a, bn1); \
    BAR(); \
    /* R3 */ \
    LDA(a, cA, 1); \
    MM(1, 0, a, bn0); \
    BAR(); \
    /* R4 */ \
    MM(1, 1, a, bn1); \
    VMW(0); \
    if ((T) < 15) { LDA(a, nA, 0); LDB(bn0, nB, 0); } \
    BAR(); \
    } while (0)

#pragma unroll 1
    for (int t2 = 0; t2 < 8; ++t2) {
        int T = 2 * t2;
        TILE(T, A0, B0, A1, B1);
        TILE((T + 1), A1, B1, A0, B0);
    }
#undef TILE
#undef STAGE
#undef LDA
#undef LDB
#undef MM
#undef BAR
#undef VMW

    int colj[4]; float bj[4];
#pragma unroll
    for (int j = 0; j < 4; j++) { colj[j] = (int)colbase + wn * 64 + j * 16 + mr; bj[j] = bias[colj[j]]; }
    int creg = (int)colbase + wn * 64;   // wave-uniform region start
    if (mode == 0) {
        // Stage C tile (256x256 bf16 = 128KB) in LDS (quad-XOR slot swizzle), coalesced copy-out.
        u16* Ct = (u16*)L;
        if (creg < 1024) {
            // Q + feature softmax over this wave's 64-col head span
#pragma unroll
            for (int i = 0; i < 8; i++) {
#pragma unroll
                for (int r = 0; r < 4; r++) {
                    int lr = wm * 128 + i * 16 + quad * 4 + r;
                    float v[4], m = -1e30f, ss = 0.f;
#pragma unroll
                    for (int j = 0; j < 4; j++) { v[j] = acc[i][j][r] + bj[j]; m = fmaxf(m, v[j]); }
#pragma unroll
                    for (int s = 1; s < 16; s <<= 1) m = fmaxf(m, __shfl_xor(m, s, 64));
#pragma unroll
                    for (int j = 0; j < 4; j++) { v[j] = __expf(v[j] - m); ss += v[j]; }
#pragma unroll
                    for (int s = 1; s < 16; s <<= 1) ss += __shfl_xor(ss, s, 64);
                    float inv = 1.f / ss;
#pragma unroll
                    for (int j = 0; j < 4; j++)
                        Ct[lr * 256 + wn * 64 + ((j ^ quad) * 16) + mr] = f2b(v[j] * inv);
                }
            }
        } else if (creg < 2048) {
            // K: store exp(k) bf16; accumulate per-column exp-sums -> colsum
            int b_ = (int)(rowbase >> 12);
            float csum[4] = {};
#pragma unroll
            for (int i = 0; i < 8; i++) {
#pragma unroll
                for (int r = 0; r < 4; r++) {
                    int lr = wm * 128 + i * 16 + quad * 4 + r;
#pragma unroll
                    for (int j = 0; j < 4; j++) {
                        float e = __expf(acc[i][j][r] + bj[j]);
                        Ct[lr * 256 + wn * 64 + ((j ^ quad) * 16) + mr] = f2b(e);
                        csum[j] += e;
                    }
                }
            }
#pragma unroll
            for (int j = 0; j < 4; j++) {
                csum[j] += __shfl_xor(csum[j], 16, 64);
                csum[j] += __shfl_xor(csum[j], 32, 64);
                if (quad == 0) atomicAdd(&colsum[b_ * 1024 + (colj[j] - 1024)], csum[j]);
            }
        } else {
            // V: plain store
#pragma unroll
            for (int i = 0; i < 8; i++) {
#pragma unroll
                for (int r = 0; r < 4; r++) {
                    int lr = wm * 128 + i * 16 + quad * 4 + r;
#pragma unroll
                    for (int j = 0; j < 4; j++)
                        Ct[lr * 256 + wn * 64 + ((j ^ quad) * 16) + mr] = f2b(acc[i][j][r] + bj[j]);
                }
            }
        }
        __syncthreads();
        u16* dst = (colIdx < 4) ? Qb : (colIdx < 8) ? Kb : Vb;
        int dcol0 = (int)colbase & 1023;
#pragma unroll
        for (int k = 0; k < 16; ++k) {
            int e = k * 512 + tid;        // 16B chunks: 256 rows x 32 chunks
            int row = e >> 5, pos = e & 31;
            int posl = pos ^ (((row >> 2) & 3) << 1);   // invert quad slot swizzle
            *(uint4*)&dst[(rowbase + row) * 1024 + dcol0 + pos * 8] =
                *(const uint4*)&Ct[row * 256 + posl * 8];
        }
        return;
    }
    // mode 2: out = Xf + gate * (A@B + bias); two 128-row LDS passes (128x256 f32 = 128KB),
    // Xf read + Cf write fused into the coalesced copy-out. (quad&1)-XOR slot swizzle.
    {
        float* Cs32 = (float*)L;
        int b_ = (int)(rowbase >> 12);
        int q1 = quad & 1;
#pragma unroll 1
        for (int pass = 0; pass < 2; ++pass) {
            if (wm == pass) {
#pragma unroll
                for (int i = 0; i < 8; i++) {
#pragma unroll
                    for (int r = 0; r < 4; r++) {
                        int lr = i * 16 + quad * 4 + r;   // 0..127 within half
#pragma unroll
                        for (int j = 0; j < 4; j++)
                            Cs32[lr * 256 + wn * 64 + ((j ^ q1) * 16) + mr] = acc[i][j][r] + bj[j];
                    }
                }
            }
            __syncthreads();
#pragma unroll
            for (int k = 0; k < 16; ++k) {
                int e = k * 512 + tid;     // 16B chunks: 128 rows x 64 chunks
                int row = e >> 6, pos = e & 63;
                int posl = pos ^ (((row >> 2) & 1) << 2);   // invert slot swizzle
                size_t grow = rowbase + pass * 128 + row;
                int col = (int)colbase + pos * 4;
                float4 c4 = *(const float4*)&Cs32[row * 256 + posl * 4];
                float4 xf = *(const float4*)&Xf[grow * 1024 + col];
                float4 g4 = *(const float4*)&gate[b_ * 1024 + col];
                float4 o;
                o.x = xf.x + g4.x * c4.x;
                o.y = xf.y + g4.y * c4.y;
                o.z = xf.z + g4.z * c4.z;
                o.w = xf.w + g4.w * c4.w;
                *(float4*)&Cf[grow * 1024 + col] = o;
            }
            __syncthreads();
        }
    }
}

// ---------------- ctx[b,h] = (expK * inv_colsum)^T V ----------------
__global__ __launch_bounds__(256) void ctx_k(
    const u16* __restrict__ kbuf, const u16* __restrict__ vbuf,
    const float* __restrict__ colsum, float* __restrict__ ctx)
{
    int ch = blockIdx.x, h = blockIdx.y, b = blockIdx.z;
    __shared__ __align__(16) float Es[16][64];
    __shared__ __align__(16) float Vs[16][64];
    int tid = threadIdx.x;
    int td = tid >> 4, tl = tid & 15;
    int lr = tid >> 4, lc = (tid & 15) * 4;    // vectorized load: row 0..15, 4-col group
    const float* cs = colsum + b * 1024 + h * 64 + lc;
    float4 inv4 = make_float4(1.f / cs[0], 1.f / cs[1], 1.f / cs[2], 1.f / cs[3]);
    float acc[4][4] = {};
    size_t rowbase = (size_t)b * 4096 + ch * 512;
    for (int g = 0; g < 32; ++g) {
        size_t base = (rowbase + g * 16 + lr) * 1024 + h * 64 + lc;
        ushort4 kv = *(const ushort4*)&kbuf[base];
        ushort4 vv = *(const ushort4*)&vbuf[base];
        *(float4*)&Es[lr][lc] = make_float4(b2f(kv.x) * inv4.x, b2f(kv.y) * inv4.y,
                                            b2f(kv.z) * inv4.z, b2f(kv.w) * inv4.w);
        *(float4*)&Vs[lr][lc] = make_float4(b2f(vv.x), b2f(vv.y), b2f(vv.z), b2f(vv.w));
        __syncthreads();
#pragma unroll
        for (int n = 0; n < 16; n++) {
            f32x4 e4 = *(const f32x4*)&Es[n][td * 4];
            f32x4 v4 = *(const f32x4*)&Vs[n][tl * 4];
#pragma unroll
            for (int i = 0; i < 4; i++)
#pragma unroll
                for (int j = 0; j < 4; j++) acc[i][j] += e4[i] * v4[j];
        }
        __syncthreads();
    }
    float* cb = ctx + (size_t)(b * 16 + h) * 4096;
#pragma unroll
    for (int i = 0; i < 4; i++)
#pragma unroll
        for (int j = 0; j < 4; j++)
            atomicAdd(&cb[(td * 4 + i) * 64 + tl * 4 + j], acc[i][j]);
}

// ---------------- emb_out = silu(emb) @ emb_W (fp32, atomic over k chunks) ----------------
__global__ __launch_bounds__(256) void embout_k(
    const float* __restrict__ emb, const float* __restrict__ embW, float* __restrict__ eo)
{
    int cb = blockIdx.x, kc = blockIdx.y;   // 8 col-blocks x 32 k-chunks of 32
    __shared__ float semb[128];
    int tid = threadIdx.x;
    if (tid < 128) {
        int b = tid >> 5, kk = tid & 31;
        float xv = emb[b * 1024 + kc * 32 + kk];
        semb[tid] = xv / (1.f + __expf(-xv));
    }
    __syncthreads();
    int o = cb * 256 + tid;
    float a0 = 0, a1 = 0, a2 = 0, a3 = 0;
    for (int kk = 0; kk < 32; kk++) {
        float wv = embW[(size_t)(kc * 32 + kk) * 2048 + o];
        a0 += semb[kk] * wv; a1 += semb[32 + kk] * wv;
        a2 += semb[64 + kk] * wv; a3 += semb[96 + kk] * wv;
    }
    atomicAdd(&eo[o], a0);
    atomicAdd(&eo[2048 + o], a1);
    atomicAdd(&eo[4096 + o], a2);
    atomicAdd(&eo[6144 + o], a3);
}

// ---------------- y = q_soft @ ctx per head (MFMA, K=64), XOR bank-swizzled Qs ----------------
__global__ __launch_bounds__(256) void y_k(
    const u16* __restrict__ q, const float* __restrict__ ctx, u16* __restrict__ y)
{
    int mc = blockIdx.x, h = blockIdx.y, b = blockIdx.z;
    __shared__ __align__(16) u16 Qs[128 * 64];
    __shared__ __align__(16) u16 Cs[64 * 72];
    int tid = threadIdx.x, lane = tid & 63, w = tid >> 6;
    size_t row0 = (size_t)b * 4096 + (size_t)mc * 128;
    const u16* Qb = q + row0 * 1024 + h * 64;
    int sr = tid >> 3, g_ = tid & 7;
    int scb = (g_ ^ (sr & 7)) * 8;   // LDS col block (swizzled); global col = g_*8
#pragma unroll
    for (int p = 0; p < 4; p++) {
        int r = p * 32 + sr;
        *(uint4*)&Qs[r * 64 + scb] = *(const uint4*)&Qb[(size_t)r * 1024 + g_ * 8];
    }
    const float* Cb = ctx + (size_t)(b * 16 + h) * 4096;
#pragma unroll
    for (int rep = 0; rep < 16; ++rep) {
        int e = tid + rep * 256;
        int d = e >> 6, l = e & 63;
        Cs[l * 72 + d] = f2b(Cb[e]);   // transposed: Cs[n=l][k=d]
    }
    __syncthreads();
    int quad = lane >> 4, mr = lane & 15;
    int swA = mr & 7;
    f32x4 acc[2][4] = {};
#pragma unroll
    for (int kk = 0; kk < 64; kk += 32) {
        bf16x8 a[2], bb[4];
#pragma unroll
        for (int i = 0; i < 2; i++)
            a[i] = *(const bf16x8*)&Qs[(w * 32 + i * 16 + mr) * 64 + ((((kk >> 3) + quad) ^ swA) * 8)];
#pragma unroll
        for (int j = 0; j < 4; j++) bb[j] = *(const bf16x8*)&Cs[(j * 16 + mr) * 72 + kk + quad * 8];
#pragma unroll
        for (int i = 0; i < 2; i++)
#pragma unroll
            for (int j = 0; j < 4; j++)
                acc[i][j] = __builtin_amdgcn_mfma_f32_16x16x32_bf16(a[i], bb[j], acc[i][j], 0, 0, 0);
    }
#pragma unroll
    for (int i = 0; i < 2; i++)
#pragma unroll
        for (int j = 0; j < 4; j++)
#pragma unroll
            for (int r = 0; r < 4; r++) {
                size_t row = row0 + w * 32 + i * 16 + quad * 4 + r;
                int col = h * 64 + j * 16 + mr;
                y[row * 1024 + col] = f2b(acc[i][j][r]);
            }
}

// ---------------- h_in = silu( LN(y)*sn_g+sn_b )*(1+scale)+shift ), bf16 in place ----------------
__global__ __launch_bounds__(256) void style_k(
    u16* __restrict__ y, const float* __restrict__ eo, const float* __restrict__ embb,
    const float* __restrict__ sng, const float* __restrict__ snb)
{
    int row = blockIdx.x, tid = threadIdx.x, b = row >> 12;
    u16* yr = y + (size_t)row * 1024;
    ushort4 u = *(const ushort4*)(yr + tid * 4);
    float vv[4] = { b2f(u.x), b2f(u.y), b2f(u.z), b2f(u.w) };
    float s = vv[0] + vv[1] + vv[2] + vv[3];
    float s2 = vv[0] * vv[0] + vv[1] * vv[1] + vv[2] * vv[2] + vv[3] * vv[3];
#pragma unroll
    for (int m = 32; m > 0; m >>= 1) { s += __shfl_xor(s, m, 64); s2 += __shfl_xor(s2, m, 64); }
    __shared__ float red[8];
    int w = tid >> 6, lane = tid & 63;
    if (lane == 0) { red[w] = s; red[4 + w] = s2; }
    __syncthreads();
    s = red[0] + red[1] + red[2] + red[3];
    s2 = red[4] + red[5] + red[6] + red[7];
    float mean = s * (1.f / 1024.f);
    float var = s2 * (1.f / 1024.f) - mean * mean;
    float rstd = rsqrtf(var + 1e-5f);
    int c = tid * 4;
    ushort4 o;
    u16* op = (u16*)&o;
#pragma unroll
    for (int i = 0; i < 4; i++) {
        int cc = c + i;
        float scale = eo[b * 2048 + cc] + embb[cc];
        float shift = eo[b * 2048 + 1024 + cc] + embb[1024 + cc];
        float hn = (vv[i] - mean) * rstd * sng[cc] + snb[cc];
        float hh = hn * (1.f + scale) + shift;
        op[i] = f2b(hh / (1.f + __expf(-hh)));
    }
    *(ushort4*)(yr + c) = o;
}

extern "C" void kernel_launch(void* const* d_in, const int* in_sizes, int n_in,
                              void* d_out, int out_size, void* d_ws, size_t ws_size,
                              hipStream_t stream)
{
    const float* x    = (const float*)d_in[0];
    const float* emb  = (const float*)d_in[1];
    const float* gate = (const float*)d_in[2];
    const float* ng   = (const float*)d_in[3];
    const float* nb   = (const float*)d_in[4];
    const float* Wq   = (const float*)d_in[5];
    const float* bq   = (const float*)d_in[6];
    const float* Wk   = (const float*)d_in[7];
    const float* bk   = (const float*)d_in[8];
    const float* Wv   = (const float*)d_in[9];
    const float* bv   = (const float*)d_in[10];
    const float* embW = (const float*)d_in[11];
    const float* embB = (const float*)d_in[12];
    const float* sng  = (const float*)d_in[13];
    const float* snb  = (const float*)d_in[14];
    const float* Wo   = (const float*)d_in[15];
    const float* ob   = (const float*)d_in[16];
    float* out = (float*)d_out;

    uint8_t* ws = (uint8_t*)d_ws;
    size_t off = 0;
    auto alloc = [&](size_t bytes) { void* p = ws + off; off += (bytes + 255) & ~(size_t)255; return p; };
    u16*   WqkvT   = (u16*)alloc(3072ull * 1024 * 2);    // 6 MB (qT | kT | vT) bf16
    u16*   WoT     = (u16*)alloc(1024ull * 1024 * 2);    // 2 MB bf16
    float* biasAll = (float*)alloc(4096 * 4);            // 16 KB
    // contiguous zero region: colsum | ctx | embout
    float* colsum  = (float*)alloc(4096 * 4);            // 16 KB
    float* ctx     = (float*)alloc(64ull * 64 * 64 * 4); // 1 MB
    float* embout  = (float*)alloc(4ull * 2048 * 4);     // 32 KB
    u16*   XN      = (u16*)alloc(16384ull * 1024 * 2);   // 32 MB: xn -> y -> h_in
    u16*   BUF0    = (u16*)alloc(16384ull * 1024 * 2);   // 32 MB: Qsoft
    u16*   BUF1    = (u16*)alloc(16384ull * 1024 * 2);   // 32 MB: expK
    u16*   BUF2    = (u16*)alloc(16384ull * 1024 * 2);   // 32 MB: V

    prep_k<<<4380, 256, 0, stream>>>(Wq, Wk, Wv, Wo, bq, bk, bv, ob, WqkvT, WoT, biasAll, colsum);
    ln_x<<<16384, 256, 0, stream>>>(x, ng, nb, XN);
    gemm256<<<dim3(12, 64), 512, 0, stream>>>(XN, WqkvT, biasAll, 0,
                                              BUF0, BUF1, BUF2, colsum, nullptr, nullptr, nullptr);
    ctx_k<<<dim3(8, 16, 4), 256, 0, stream>>>(BUF1, BUF2, colsum, ctx);
    embout_k<<<dim3(8, 32), 256, 0, stream>>>(emb, embW, embout);
    y_k<<<dim3(32, 16, 4), 256, 0, stream>>>(BUF0, ctx, XN);
    style_k<<<16384, 256, 0, stream>>>(XN, embout, embB, sng, snb);
    gemm256<<<dim3(4, 64), 512, 0, stream>>>(XN, WoT, biasAll + 3072, 2,
                                             nullptr, nullptr, nullptr, nullptr, out, x, gate);
}

// Round 7
// 412.726 us; speedup vs baseline: 1.0279x; 1.0097x over previous
//
#include <hip/hip_runtime.h>
#include <stdint.h>

typedef unsigned short u16;
typedef float f32x4 __attribute__((ext_vector_type(4)));
typedef __bf16 bf16x8 __attribute__((ext_vector_type(8)));

__device__ __forceinline__ float b2f(u16 u) {
    union { unsigned int i; float f; } w; w.i = ((unsigned int)u) << 16; return w.f;
}
__device__ __forceinline__ u16 f2b(float f) {
    union { float f; unsigned int i; } w; w.f = f;
    unsigned int r = w.i + 0x7fffu + ((w.i >> 16) & 1u);
    return (u16)(r >> 16);
}
__device__ __forceinline__ void gload16(const void* g, void* l) {
    __builtin_amdgcn_global_load_lds(
        (const __attribute__((address_space(1))) unsigned int*)g,
        (__attribute__((address_space(3))) unsigned int*)l, 16, 0, 0);
}

// ---------------- prep: transpose+cast 4 weights, pack biases, zero scratch ----------------
__global__ __launch_bounds__(256) void prep_k(
    const float* __restrict__ Wq, const float* __restrict__ Wk, const float* __restrict__ Wv,
    const float* __restrict__ Wo, const float* __restrict__ bq, const float* __restrict__ bk,
    const float* __restrict__ bv, const float* __restrict__ ob,
    u16* __restrict__ WqkvT, u16* __restrict__ WoT, float* __restrict__ biasAll,
    float* __restrict__ zeroBase)
{
    int bz = blockIdx.x, tid = threadIdx.x;
    if (bz < 4096) {
        int z = bz >> 10, rem = bz & 1023;
        const float* src = (z == 0) ? Wq : (z == 1) ? Wk : (z == 2) ? Wv : Wo;
        u16* dst = (z < 3) ? (WqkvT + (size_t)z * 1024 * 1024) : WoT;
        __shared__ u16 tile[32][33];
        int tx = tid & 31, ty = tid >> 5;  // 32 x 8
        int n0 = (rem & 31) * 32, k0 = (rem >> 5) * 32;
#pragma unroll
        for (int i = 0; i < 4; i++) tile[ty + 8 * i][tx] = f2b(src[(size_t)(k0 + ty + 8 * i) * 1024 + n0 + tx]);
        __syncthreads();
#pragma unroll
        for (int i = 0; i < 4; i++) dst[(size_t)(n0 + ty + 8 * i) * 1024 + k0 + tx] = tile[tx][ty + 8 * i];
    } else if (bz < 4112) {
        int i = (bz - 4096) * 256 + tid;
        float v;
        if (i < 1024) v = bq[i];
        else if (i < 2048) v = bk[i - 1024];
        else if (i < 3072) v = bv[i - 2048];
        else v = ob[i - 3072];
        biasAll[i] = v;
    } else {
        int e = (bz - 4112) * 256 + tid;           // float4 index
        ((float4*)zeroBase)[e] = make_float4(0.f, 0.f, 0.f, 0.f);
    }
}

// ---------------- LayerNorm(x fp32) -> xn (bf16), one row per block ----------------
__global__ __launch_bounds__(256) void ln_x(
    const float* __restrict__ x, const float* __restrict__ g, const float* __restrict__ bt,
    u16* __restrict__ xn)
{
    int row = blockIdx.x, tid = threadIdx.x;
    const float* xr = x + (size_t)row * 1024;
    float4 u = *(const float4*)(xr + tid * 4);
    float v0 = u.x, v1 = u.y, v2 = u.z, v3 = u.w;
    float s = v0 + v1 + v2 + v3;
    float s2 = v0 * v0 + v1 * v1 + v2 * v2 + v3 * v3;
#pragma unroll
    for (int m = 32; m > 0; m >>= 1) { s += __shfl_xor(s, m, 64); s2 += __shfl_xor(s2, m, 64); }
    __shared__ float red[8];
    int w = tid >> 6, lane = tid & 63;
    if (lane == 0) { red[w] = s; red[4 + w] = s2; }
    __syncthreads();
    s = red[0] + red[1] + red[2] + red[3];
    s2 = red[4] + red[5] + red[6] + red[7];
    float mean = s * (1.f / 1024.f);
    float var = s2 * (1.f / 1024.f) - mean * mean;
    float rstd = rsqrtf(var + 1e-5f);
    int c = tid * 4;
    float4 gg = *(const float4*)(g + c);
    float4 bb = *(const float4*)(bt + c);
    ushort4 o;
    o.x = f2b((v0 - mean) * rstd * gg.x + bb.x);
    o.y = f2b((v1 - mean) * rstd * gg.y + bb.y);
    o.z = f2b((v2 - mean) * rstd * gg.z + bb.z);
    o.w = f2b((v3 - mean) * rstd * gg.w + bb.w);
    *(ushort4*)(xn + (size_t)row * 1024 + c) = o;
}

// ---------------- 256x256 MFMA GEMM, BK=64, 8 waves ----------------------------------------
// R7 loop: counted vmcnt, never drains to 0 mid-loop (T4 discipline).
//  R1: stage A'(4 ops); VMW(4) [proves B_T landed, A' in flight]; LDB bn0,bn1; MM(0,0) | BAR
//  R2: stage B'(4 ops); MM(0,1)                                                        | BAR
//  R3: LDA(a,cur,1);    MM(1,0)                                                        | BAR
//  R4: MM(1,1); VMW(4) [proves A' landed, B' in flight]; LDA(a,nxt,0)                  | BAR
// Last tile: VMW(0) at R1, stages/preloads skipped. Epilogues = verified R5 (quad-XOR
// slot swizzle, conflict-free LDS C-staging, coalesced copy-out).
__global__ __launch_bounds__(512, 2) void gemm256(
    const u16* __restrict__ A, const u16* __restrict__ Bt, const float* __restrict__ bias,
    int mode, u16* __restrict__ Qb, u16* __restrict__ Kb, u16* __restrict__ Vb,
    float* __restrict__ colsum, float* __restrict__ Cf,
    const float* __restrict__ Xf, const float* __restrict__ gate)
{
    const int K = 1024;
    __shared__ __align__(16) u16 L[2][2][256 * 64];   // [buf][0=A,1=B] 128 KB total
    int tid = threadIdx.x, lane = tid & 63, w = tid >> 6;
    int wm = w >> 2, wn = w & 3;
    // XCD swizzle: each XCD owns 8 row-tiles (4MB of A), walks cols outer.
    int NB = gridDim.x;
    int lid = blockIdx.y * NB + blockIdx.x;
    int xcd = lid & 7;
    int i_ = lid >> 3;
    int rowLocal = i_ & 7;
    int colIdx = i_ >> 3;
    size_t rowbase = (size_t)(xcd * 8 + rowLocal) * 256;
    size_t colbase = (size_t)colIdx * 256;
    const u16* Ab = A + rowbase * K;
    const u16* Bb = Bt + colbase * K;
    f32x4 acc[8][4] = {};
    int quad = lane >> 4, mr = lane & 15, swK = mr & 7;
    int srow = lane >> 3;
    int scol = ((lane & 7) ^ srow) * 8;   // pre-swizzled global col (16B blocks)
    u16* A0 = L[0][0]; u16* B0 = L[0][1]; u16* A1 = L[1][0]; u16* B1 = L[1][1];

#define STAGE(ldsmat, gbase, hf, k0) do { \
    _Pragma("unroll") \
    for (int r_ = 0; r_ < 2; r_++) { \
        int rb_ = (hf) * 128 + r_ * 64 + w * 8; \
        gload16((gbase) + (size_t)(rb_ + srow) * 1024 + (k0) + scol, (ldsmat) + rb_ * 64); \
    } } while (0)

#define LDA(dst, src, mh) do { \
    _Pragma("unroll") \
    for (int i2_ = 0; i2_ < 4; i2_++) \
    _Pragma("unroll") \
    for (int kq_ = 0; kq_ < 2; kq_++) \
        dst[i2_ * 2 + kq_] = *(const bf16x8*)&(src)[(wm * 128 + (mh) * 64 + i2_ * 16 + mr) * 64 + (((kq_ * 4 + quad) ^ swK) * 8)]; \
    } while (0)

#define LDB(dst, src, nh) do { \
    _Pragma("unroll") \
    for (int j_ = 0; j_ < 2; j_++) \
    _Pragma("unroll") \
    for (int kq_ = 0; kq_ < 2; kq_++) \
        dst[j_ * 2 + kq_] = *(const bf16x8*)&(src)[(wn * 64 + (nh) * 32 + j_ * 16 + mr) * 64 + (((kq_ * 4 + quad) ^ swK) * 8)]; \
    } while (0)

#define MM(mh, nh, av, bv) do { \
    __builtin_amdgcn_s_setprio(1); \
    _Pragma("unroll") \
    for (int i2_ = 0; i2_ < 4; i2_++) \
    _Pragma("unroll") \
    for (int j_ = 0; j_ < 2; j_++) \
    _Pragma("unroll") \
    for (int kq_ = 0; kq_ < 2; kq_++) \
        acc[(mh) * 4 + i2_][(nh) * 2 + j_] = __builtin_amdgcn_mfma_f32_16x16x32_bf16( \
            av[i2_ * 2 + kq_], bv[j_ * 2 + kq_], acc[(mh) * 4 + i2_][(nh) * 2 + j_], 0, 0, 0); \
    __builtin_amdgcn_s_setprio(0); } while (0)

#define BAR() asm volatile("s_barrier" ::: "memory")
#define VMW(n) asm volatile("s_waitcnt vmcnt(" #n ")" ::: "memory")

    // prologue: tile0 A+B staged (8 ops); wait A0 only (counted), preload A-frags
    STAGE(A0, Ab, 0, 0); STAGE(A0, Ab, 1, 0);
    STAGE(B0, Bb, 0, 0); STAGE(B0, Bb, 1, 0);
    VMW(4);              // A0 (oldest 4) landed; B0 may be in flight
    BAR();

    bf16x8 a[8], bn0[4], bn1[4];
    LDA(a, A0, 0);

    // Per tile T (cur = bufs of T, nxt = bufs of T+1):
#define TILE(T, cA, cB, nA, nB) do { \
    const int kN_ = ((T) + 1) * 64; \
    /* R1 */ \
    if ((T) < 15) { STAGE(nA, Ab, 0, kN_); STAGE(nA, Ab, 1, kN_); VMW(4); } \
    else { VMW(0); } \
    LDB(bn0, cB, 0); LDB(bn1, cB, 1); \
    MM(0, 0, a, bn0); \
    BAR(); \
    /* R2 */ \
    if ((T) < 15) { STAGE(nB, Bb, 0, kN_); STAGE(nB, Bb, 1, kN_); } \
    MM(0, 1, a, bn1); \
    BAR(); \
    /* R3 */ \
    LDA(a, cA, 1); \
    MM(1, 0, a, bn0); \
    BAR(); \
    /* R4 */ \
    MM(1, 1, a, bn1); \
    if ((T) < 15) { VMW(4); LDA(a, nA, 0); } \
    BAR(); \
    } while (0)

#pragma unroll 1
    for (int t2 = 0; t2 < 8; ++t2) {
        int T = 2 * t2;
        TILE(T, A0, B0, A1, B1);
        TILE((T + 1), A1, B1, A0, B0);
    }
#undef TILE
#undef STAGE
#undef LDA
#undef LDB
#undef MM
#undef BAR
#undef VMW

    int colj[4]; float bj[4];
#pragma unroll
    for (int j = 0; j < 4; j++) { colj[j] = (int)colbase + wn * 64 + j * 16 + mr; bj[j] = bias[colj[j]]; }
    int creg = (int)colbase + wn * 64;   // wave-uniform region start
    if (mode == 0) {
        // Stage C tile (256x256 bf16 = 128KB) in LDS (quad-XOR slot swizzle), coalesced copy-out.
        u16* Ct = (u16*)L;
        if (creg < 1024) {
            // Q + feature softmax over this wave's 64-col head span
#pragma unroll
            for (int i = 0; i < 8; i++) {
#pragma unroll
                for (int r = 0; r < 4; r++) {
                    int lr = wm * 128 + i * 16 + quad * 4 + r;
                    float v[4], m = -1e30f, ss = 0.f;
#pragma unroll
                    for (int j = 0; j < 4; j++) { v[j] = acc[i][j][r] + bj[j]; m = fmaxf(m, v[j]); }
#pragma unroll
                    for (int s = 1; s < 16; s <<= 1) m = fmaxf(m, __shfl_xor(m, s, 64));
#pragma unroll
                    for (int j = 0; j < 4; j++) { v[j] = __expf(v[j] - m); ss += v[j]; }
#pragma unroll
                    for (int s = 1; s < 16; s <<= 1) ss += __shfl_xor(ss, s, 64);
                    float inv = 1.f / ss;
#pragma unroll
                    for (int j = 0; j < 4; j++)
                        Ct[lr * 256 + wn * 64 + ((j ^ quad) * 16) + mr] = f2b(v[j] * inv);
                }
            }
        } else if (creg < 2048) {
            // K: store exp(k) bf16; accumulate per-column exp-sums -> colsum
            int b_ = (int)(rowbase >> 12);
            float csum[4] = {};
#pragma unroll
            for (int i = 0; i < 8; i++) {
#pragma unroll
                for (int r = 0; r < 4; r++) {
                    int lr = wm * 128 + i * 16 + quad * 4 + r;
#pragma unroll
                    for (int j = 0; j < 4; j++) {
                        float e = __expf(acc[i][j][r] + bj[j]);
                        Ct[lr * 256 + wn * 64 + ((j ^ quad) * 16) + mr] = f2b(e);
                        csum[j] += e;
                    }
                }
            }
#pragma unroll
            for (int j = 0; j < 4; j++) {
                csum[j] += __shfl_xor(csum[j], 16, 64);
                csum[j] += __shfl_xor(csum[j], 32, 64);
                if (quad == 0) atomicAdd(&colsum[b_ * 1024 + (colj[j] - 1024)], csum[j]);
            }
        } else {
            // V: plain store
#pragma unroll
            for (int i = 0; i < 8; i++) {
#pragma unroll
                for (int r = 0; r < 4; r++) {
                    int lr = wm * 128 + i * 16 + quad * 4 + r;
#pragma unroll
                    for (int j = 0; j < 4; j++)
                        Ct[lr * 256 + wn * 64 + ((j ^ quad) * 16) + mr] = f2b(acc[i][j][r] + bj[j]);
                }
            }
        }
        __syncthreads();
        u16* dst = (colIdx < 4) ? Qb : (colIdx < 8) ? Kb : Vb;
        int dcol0 = (int)colbase & 1023;
#pragma unroll
        for (int k = 0; k < 16; ++k) {
            int e = k * 512 + tid;        // 16B chunks: 256 rows x 32 chunks
            int row = e >> 5, pos = e & 31;
            int posl = pos ^ (((row >> 2) & 3) << 1);   // invert quad slot swizzle
            *(uint4*)&dst[(rowbase + row) * 1024 + dcol0 + pos * 8] =
                *(const uint4*)&Ct[row * 256 + posl * 8];
        }
        return;
    }
    // mode 2: out = Xf + gate * (A@B + bias); two 128-row LDS passes (128x256 f32 = 128KB),
    // Xf read + Cf write fused into the coalesced copy-out. (quad&1)-XOR slot swizzle.
    {
        float* Cs32 = (float*)L;
        int b_ = (int)(rowbase >> 12);
        int q1 = quad & 1;
#pragma unroll 1
        for (int pass = 0; pass < 2; ++pass) {
            if (wm == pass) {
#pragma unroll
                for (int i = 0; i < 8; i++) {
#pragma unroll
                    for (int r = 0; r < 4; r++) {
                        int lr = i * 16 + quad * 4 + r;   // 0..127 within half
#pragma unroll
                        for (int j = 0; j < 4; j++)
                            Cs32[lr * 256 + wn * 64 + ((j ^ q1) * 16) + mr] = acc[i][j][r] + bj[j];
                    }
                }
            }
            __syncthreads();
#pragma unroll
            for (int k = 0; k < 16; ++k) {
                int e = k * 512 + tid;     // 16B chunks: 128 rows x 64 chunks
                int row = e >> 6, pos = e & 63;
                int posl = pos ^ (((row >> 2) & 1) << 2);   // invert slot swizzle
                size_t grow = rowbase + pass * 128 + row;
                int col = (int)colbase + pos * 4;
                float4 c4 = *(const float4*)&Cs32[row * 256 + posl * 4];
                float4 xf = *(const float4*)&Xf[grow * 1024 + col];
                float4 g4 = *(const float4*)&gate[b_ * 1024 + col];
                float4 o;
                o.x = xf.x + g4.x * c4.x;
                o.y = xf.y + g4.y * c4.y;
                o.z = xf.z + g4.z * c4.z;
                o.w = xf.w + g4.w * c4.w;
                *(float4*)&Cf[grow * 1024 + col] = o;
            }
            __syncthreads();
        }
    }
}

// ---------------- ctx[b,h] = (expK * inv_colsum)^T V ----------------
__global__ __launch_bounds__(256) void ctx_k(
    const u16* __restrict__ kbuf, const u16* __restrict__ vbuf,
    const float* __restrict__ colsum, float* __restrict__ ctx)
{
    int ch = blockIdx.x, h = blockIdx.y, b = blockIdx.z;
    __shared__ __align__(16) float Es[16][64];
    __shared__ __align__(16) float Vs[16][64];
    int tid = threadIdx.x;
    int td = tid >> 4, tl = tid & 15;
    int lr = tid >> 4, lc = (tid & 15) * 4;    // vectorized load: row 0..15, 4-col group
    const float* cs = colsum + b * 1024 + h * 64 + lc;
    float4 inv4 = make_float4(1.f / cs[0], 1.f / cs[1], 1.f / cs[2], 1.f / cs[3]);
    float acc[4][4] = {};
    size_t rowbase = (size_t)b * 4096 + ch * 512;
    for (int g = 0; g < 32; ++g) {
        size_t base = (rowbase + g * 16 + lr) * 1024 + h * 64 + lc;
        ushort4 kv = *(const ushort4*)&kbuf[base];
        ushort4 vv = *(const ushort4*)&vbuf[base];
        *(float4*)&Es[lr][lc] = make_float4(b2f(kv.x) * inv4.x, b2f(kv.y) * inv4.y,
                                            b2f(kv.z) * inv4.z, b2f(kv.w) * inv4.w);
        *(float4*)&Vs[lr][lc] = make_float4(b2f(vv.x), b2f(vv.y), b2f(vv.z), b2f(vv.w));
        __syncthreads();
#pragma unroll
        for (int n = 0; n < 16; n++) {
            f32x4 e4 = *(const f32x4*)&Es[n][td * 4];
            f32x4 v4 = *(const f32x4*)&Vs[n][tl * 4];
#pragma unroll
            for (int i = 0; i < 4; i++)
#pragma unroll
                for (int j = 0; j < 4; j++) acc[i][j] += e4[i] * v4[j];
        }
        __syncthreads();
    }
    float* cb = ctx + (size_t)(b * 16 + h) * 4096;
#pragma unroll
    for (int i = 0; i < 4; i++)
#pragma unroll
        for (int j = 0; j < 4; j++)
            atomicAdd(&cb[(td * 4 + i) * 64 + tl * 4 + j], acc[i][j]);
}

// ---------------- emb_out = silu(emb) @ emb_W (fp32, atomic over k chunks) ----------------
__global__ __launch_bounds__(256) void embout_k(
    const float* __restrict__ emb, const float* __restrict__ embW, float* __restrict__ eo)
{
    int cb = blockIdx.x, kc = blockIdx.y;   // 8 col-blocks x 32 k-chunks of 32
    __shared__ float semb[128];
    int tid = threadIdx.x;
    if (tid < 128) {
        int b = tid >> 5, kk = tid & 31;
        float xv = emb[b * 1024 + kc * 32 + kk];
        semb[tid] = xv / (1.f + __expf(-xv));
    }
    __syncthreads();
    int o = cb * 256 + tid;
    float a0 = 0, a1 = 0, a2 = 0, a3 = 0;
    for (int kk = 0; kk < 32; kk++) {
        float wv = embW[(size_t)(kc * 32 + kk) * 2048 + o];
        a0 += semb[kk] * wv; a1 += semb[32 + kk] * wv;
        a2 += semb[64 + kk] * wv; a3 += semb[96 + kk] * wv;
    }
    atomicAdd(&eo[o], a0);
    atomicAdd(&eo[2048 + o], a1);
    atomicAdd(&eo[4096 + o], a2);
    atomicAdd(&eo[6144 + o], a3);
}

// ---------------- y = q_soft @ ctx per head (MFMA, K=64), XOR bank-swizzled Qs ----------------
__global__ __launch_bounds__(256) void y_k(
    const u16* __restrict__ q, const float* __restrict__ ctx, u16* __restrict__ y)
{
    int mc = blockIdx.x, h = blockIdx.y, b = blockIdx.z;
    __shared__ __align__(16) u16 Qs[128 * 64];
    __shared__ __align__(16) u16 Cs[64 * 72];
    int tid = threadIdx.x, lane = tid & 63, w = tid >> 6;
    size_t row0 = (size_t)b * 4096 + (size_t)mc * 128;
    const u16* Qb = q + row0 * 1024 + h * 64;
    int sr = tid >> 3, g_ = tid & 7;
    int scb = (g_ ^ (sr & 7)) * 8;   // LDS col block (swizzled); global col = g_*8
#pragma unroll
    for (int p = 0; p < 4; p++) {
        int r = p * 32 + sr;
        *(uint4*)&Qs[r * 64 + scb] = *(const uint4*)&Qb[(size_t)r * 1024 + g_ * 8];
    }
    const float* Cb = ctx + (size_t)(b * 16 + h) * 4096;
#pragma unroll
    for (int rep = 0; rep < 16; ++rep) {
        int e = tid + rep * 256;
        int d = e >> 6, l = e & 63;
        Cs[l * 72 + d] = f2b(Cb[e]);   // transposed: Cs[n=l][k=d]
    }
    __syncthreads();
    int quad = lane >> 4, mr = lane & 15;
    int swA = mr & 7;
    f32x4 acc[2][4] = {};
#pragma unroll
    for (int kk = 0; kk < 64; kk += 32) {
        bf16x8 a[2], bb[4];
#pragma unroll
        for (int i = 0; i < 2; i++)
            a[i] = *(const bf16x8*)&Qs[(w * 32 + i * 16 + mr) * 64 + ((((kk >> 3) + quad) ^ swA) * 8)];
#pragma unroll
        for (int j = 0; j < 4; j++) bb[j] = *(const bf16x8*)&Cs[(j * 16 + mr) * 72 + kk + quad * 8];
#pragma unroll
        for (int i = 0; i < 2; i++)
#pragma unroll
            for (int j = 0; j < 4; j++)
                acc[i][j] = __builtin_amdgcn_mfma_f32_16x16x32_bf16(a[i], bb[j], acc[i][j], 0, 0, 0);
    }
#pragma unroll
    for (int i = 0; i < 2; i++)
#pragma unroll
        for (int j = 0; j < 4; j++)
#pragma unroll
            for (int r = 0; r < 4; r++) {
                size_t row = row0 + w * 32 + i * 16 + quad * 4 + r;
                int col = h * 64 + j * 16 + mr;
                y[row * 1024 + col] = f2b(acc[i][j][r]);
            }
}

// ---------------- h_in = silu( LN(y)*sn_g+sn_b )*(1+scale)+shift ), bf16 in place ----------------
__global__ __launch_bounds__(256) void style_k(
    u16* __restrict__ y, const float* __restrict__ eo, const float* __restrict__ embb,
    const float* __restrict__ sng, const float* __restrict__ snb)
{
    int row = blockIdx.x, tid = threadIdx.x, b = row >> 12;
    u16* yr = y + (size_t)row * 1024;
    ushort4 u = *(const ushort4*)(yr + tid * 4);
    float vv[4] = { b2f(u.x), b2f(u.y), b2f(u.z), b2f(u.w) };
    float s = vv[0] + vv[1] + vv[2] + vv[3];
    float s2 = vv[0] * vv[0] + vv[1] * vv[1] + vv[2] * vv[2] + vv[3] * vv[3];
#pragma unroll
    for (int m = 32; m > 0; m >>= 1) { s += __shfl_xor(s, m, 64); s2 += __shfl_xor(s2, m, 64); }
    __shared__ float red[8];
    int w = tid >> 6, lane = tid & 63;
    if (lane == 0) { red[w] = s; red[4 + w] = s2; }
    __syncthreads();
    s = red[0] + red[1] + red[2] + red[3];
    s2 = red[4] + red[5] + red[6] + red[7];
    float mean = s * (1.f / 1024.f);
    float var = s2 * (1.f / 1024.f) - mean * mean;
    float rstd = rsqrtf(var + 1e-5f);
    int c = tid * 4;
    ushort4 o;
    u16* op = (u16*)&o;
#pragma unroll
    for (int i = 0; i < 4; i++) {
        int cc = c + i;
        float scale = eo[b * 2048 + cc] + embb[cc];
        float shift = eo[b * 2048 + 1024 + cc] + embb[1024 + cc];
        float hn = (vv[i] - mean) * rstd * sng[cc] + snb[cc];
        float hh = hn * (1.f + scale) + shift;
        op[i] = f2b(hh / (1.f + __expf(-hh)));
    }
    *(ushort4*)(yr + c) = o;
}

extern "C" void kernel_launch(void* const* d_in, const int* in_sizes, int n_in,
                              void* d_out, int out_size, void* d_ws, size_t ws_size,
                              hipStream_t stream)
{
    const float* x    = (const float*)d_in[0];
    const float* emb  = (const float*)d_in[1];
    const float* gate = (const float*)d_in[2];
    const float* ng   = (const float*)d_in[3];
    const float* nb   = (const float*)d_in[4];
    const float* Wq   = (const float*)d_in[5];
    const float* bq   = (const float*)d_in[6];
    const float* Wk   = (const float*)d_in[7];
    const float* bk   = (const float*)d_in[8];
    const float* Wv   = (const float*)d_in[9];
    const float* bv   = (const float*)d_in[10];
    const float* embW = (const float*)d_in[11];
    const float* embB = (const float*)d_in[12];
    const float* sng  = (const float*)d_in[13];
    const float* snb  = (const float*)d_in[14];
    const float* Wo   = (const float*)d_in[15];
    const float* ob   = (const float*)d_in[16];
    float* out = (float*)d_out;

    uint8_t* ws = (uint8_t*)d_ws;
    size_t off = 0;
    auto alloc = [&](size_t bytes) { void* p = ws + off; off += (bytes + 255) & ~(size_t)255; return p; };
    u16*   WqkvT   = (u16*)alloc(3072ull * 1024 * 2);    // 6 MB (qT | kT | vT) bf16
    u16*   WoT     = (u16*)alloc(1024ull * 1024 * 2);    // 2 MB bf16
    float* biasAll = (float*)alloc(4096 * 4);            // 16 KB
    // contiguous zero region: colsum | ctx | embout
    float* colsum  = (float*)alloc(4096 * 4);            // 16 KB
    float* ctx     = (float*)alloc(64ull * 64 * 64 * 4); // 1 MB
    float* embout  = (float*)alloc(4ull * 2048 * 4);     // 32 KB
    u16*   XN      = (u16*)alloc(16384ull * 1024 * 2);   // 32 MB: xn -> y -> h_in
    u16*   BUF0    = (u16*)alloc(16384ull * 1024 * 2);   // 32 MB: Qsoft
    u16*   BUF1    = (u16*)alloc(16384ull * 1024 * 2);   // 32 MB: expK
    u16*   BUF2    = (u16*)alloc(16384ull * 1024 * 2);   // 32 MB: V

    prep_k<<<4380, 256, 0, stream>>>(Wq, Wk, Wv, Wo, bq, bk, bv, ob, WqkvT, WoT, biasAll, colsum);
    ln_x<<<16384, 256, 0, stream>>>(x, ng, nb, XN);
    gemm256<<<dim3(12, 64), 512, 0, stream>>>(XN, WqkvT, biasAll, 0,
                                              BUF0, BUF1, BUF2, colsum, nullptr, nullptr, nullptr);
    ctx_k<<<dim3(8, 16, 4), 256, 0, stream>>>(BUF1, BUF2, colsum, ctx);
    embout_k<<<dim3(8, 32), 256, 0, stream>>>(emb, embW, embout);
    y_k<<<dim3(32, 16, 4), 256, 0, stream>>>(BUF0, ctx, XN);
    style_k<<<16384, 256, 0, stream>>>(XN, embout, embB, sng, snb);
    gemm256<<<dim3(4, 64), 512, 0, stream>>>(XN, WoT, biasAll + 3072, 2,
                                             nullptr, nullptr, nullptr, nullptr, out, x, gate);
}